// Round 12
// baseline (313.400 us; speedup 1.0000x reference)
//
#include <hip/hip_runtime.h>

#define DI __device__ __forceinline__

typedef __bf16 bf16_t;
typedef __bf16 bf16x4 __attribute__((ext_vector_type(4)));
typedef __bf16 bf16x8 __attribute__((ext_vector_type(8)));
typedef float f32x4 __attribute__((ext_vector_type(4)));
typedef unsigned long long u64;

// Problem constants
// B=64, N=512, F=64, H=128, FO=64, K=16

DI bf16_t f2b(float f) {
  unsigned u = __float_as_uint(f);
  unsigned r = (u + 0x7fffu + ((u >> 16) & 1u)) >> 16;
  return __builtin_bit_cast(bf16_t, (unsigned short)r);
}
DI float b2f(bf16_t h) {
  return __uint_as_float(((unsigned)__builtin_bit_cast(unsigned short, h)) << 16);
}
DI f32x4 zero4() { f32x4 z = {0.f, 0.f, 0.f, 0.f}; return z; }

DI u64 u64min(u64 a, u64 b) { return a < b ? a : b; }
// ctrl must be an ICE for __builtin_amdgcn_update_dpp -> template parameter.
template <int CTRL>
DI u64 dpp_u64(u64 v) {
  int lo = (int)(unsigned)(v & 0xffffffffull);
  int hi = (int)(unsigned)(v >> 32);
  int tlo = __builtin_amdgcn_update_dpp(0, lo, CTRL, 0xF, 0xF, true);
  int thi = __builtin_amdgcn_update_dpp(0, hi, CTRL, 0xF, 0xF, true);
  return (((u64)(unsigned)thi) << 32) | (unsigned)tlo;
}
template <int CTRL>
DI float dpp_f32(float v) {
  int t = __builtin_amdgcn_update_dpp(0, (int)__float_as_uint(v), CTRL, 0xF, 0xF, true);
  return __uint_as_float((unsigned)t);
}
// Min over each 16-lane row; result uniform within the row.
DI u64 rowmin_u64(u64 v) {
  v = u64min(v, dpp_u64<0xB1>(v));
  v = u64min(v, dpp_u64<0x4E>(v));
  v = u64min(v, dpp_u64<0x141>(v));
  v = u64min(v, dpp_u64<0x140>(v));
  return v;
}
// Sum over each 16-lane row (butterfly); result uniform within the row.
DI float rowsum_f32(float v) {
  v += dpp_f32<0xB1>(v);
  v += dpp_f32<0x4E>(v);
  v += dpp_f32<0x141>(v);
  v += dpp_f32<0x140>(v);
  return v;
}
// Bitonic sort, 16 elements, ascending. 80 CAS, all indices compile-time.
DI void bitonic16(u64* a) {
#pragma unroll
  for (int k = 2; k <= 16; k <<= 1)
#pragma unroll
    for (int j = k >> 1; j > 0; j >>= 1)
#pragma unroll
      for (int i = 0; i < 16; ++i) {
        const int l = i ^ j;
        if (l > i) {
          const bool up = ((i & k) == 0);
          const bool sw = up ? (a[i] > a[l]) : (a[i] < a[l]);
          const u64 t0 = a[i], t1 = a[l];
          a[i] = sw ? t1 : t0;
          a[l] = sw ? t0 : t1;
        }
      }
}

// ---------------- Kernel P: pack weights into split-bf16 MFMA B-fragment layout ----
__global__ void kpack(const float* __restrict__ We1, const float* __restrict__ We2,
                      const float* __restrict__ Wn1, const float* __restrict__ Wn2,
                      bf16_t* __restrict__ W1p, bf16_t* __restrict__ W2p,
                      bf16_t* __restrict__ Wn1p, bf16_t* __restrict__ Wn2p) {
  int p = blockIdx.x * 256 + threadIdx.x;  // 0..16383
  const float* W; bf16_t* dst; int K, Nn, local, mode;
  if (p < 4096)       { W = We1; dst = W1p;  K = 128; Nn = 128; mode = 0; local = p; }
  else if (p < 8192)  { W = We2; dst = W2p;  K = 128; Nn = 128; mode = 1; local = p - 4096; }
  else if (p < 14336) { W = Wn1; dst = Wn1p; K = 192; Nn = 128; mode = 0; local = p - 8192; }
  else                { W = Wn2; dst = Wn2p; K = 128; Nn = 64;  mode = 1; local = p - 14336; }
  int lane = local & 63;
  int nnt = (Nn >> 4);
  int chunk = local >> 6;
  int nt = chunk % nnt;
  int s = chunk / nnt;
  int n = nt * 16 + (lane & 15);
  int kbase = s * 32 + ((lane >> 4) * 8);
  bf16x8 v;
#pragma unroll
  for (int j = 0; j < 8; ++j) {
    int kp = kbase + j;
    int region = kp / K;
    int kk = kp - region * K;
    float w = W[kk * Nn + n];
    bf16_t hi = f2b(w);
    v[j] = (mode == 1 && region == 1) ? f2b(w - b2f(hi)) : hi;
  }
  *(bf16x8*)(dst + (size_t)local * 8) = v;
}

// ---------------- Kernel A: x, xhi/xlo planes, sq, per-batch compaction ------------
__global__ void __launch_bounds__(256) kprep(const float* __restrict__ nodes,
    const int* __restrict__ mask, float* __restrict__ x,
    bf16_t* __restrict__ xhi, bf16_t* __restrict__ xlo,
    float* __restrict__ sq, int* __restrict__ vlist, int* __restrict__ vcnt) {
  const int b = blockIdx.x, t = threadIdx.x, lane = t & 63, w = t >> 6;
  __shared__ int cnts[8];
  __shared__ int basep[8];
  unsigned long long bal[2]; int flag[2];
#pragma unroll
  for (int h = 0; h < 2; ++h) {
    const int n = h * 256 + t;
    const size_t ro = (size_t)(b * 512 + n) * 64;
    const int mk = mask[b * 512 + n];
    const float fm = (float)mk;
    float s = 0.f;
#pragma unroll
    for (int c = 0; c < 64; c += 4) {
      float4 v = *(const float4*)(nodes + ro + c);
      v.x *= fm; v.y *= fm; v.z *= fm; v.w *= fm;
      *(float4*)(x + ro + c) = v;
      float vv[4] = {v.x, v.y, v.z, v.w};
      bf16x4 hh, ll;
#pragma unroll
      for (int k = 0; k < 4; ++k) {
        bf16_t hi = f2b(vv[k]);
        hh[k] = hi;
        ll[k] = f2b(vv[k] - b2f(hi));
      }
      *(bf16x4*)(xhi + ro + c) = hh;
      *(bf16x4*)(xlo + ro + c) = ll;
      s += v.x * v.x + v.y * v.y + v.z * v.z + v.w * v.w;
    }
    sq[b * 512 + n] = s;
    flag[h] = (mk != 0);
    bal[h] = __ballot(flag[h]);
    if (lane == 0) cnts[h * 4 + w] = __popcll(bal[h]);
  }
  __syncthreads();
  if (t == 0) {
    int a = 0;
    for (int c = 0; c < 8; ++c) { basep[c] = a; a += cnts[c]; }
    vcnt[b] = a;
  }
  __syncthreads();
#pragma unroll
  for (int h = 0; h < 2; ++h) {
    if (flag[h]) {
      const unsigned long long lt = (lane == 0) ? 0ull : (~0ull >> (64 - lane));
      const int pos = basep[h * 4 + w] + __popcll(bal[h] & lt);
      vlist[b * 512 + pos] = h * 256 + t;
    }
  }
}

// ---------------- Kernel B: distances + top-16 (self excluded), row-parallel -------
// (unchanged from r8)
__global__ void __launch_bounds__(256) kknn(const float* __restrict__ x,
    const float* __restrict__ sq, const int* __restrict__ vlist,
    const int* __restrict__ vcnt, int* __restrict__ idxg) {
  const int b = blockIdx.x & 63, tile = blockIdx.x >> 6;
  const int nv = vcnt[b];
  if (tile * 16 >= nv) return;  // block-uniform, before any barrier
  const int t = threadIdx.x, lane = t & 63, w = t >> 6;
  const int i = lane >> 4, d = lane & 15;
  __shared__ float sqs[512];
  __shared__ int vls[512];
  __shared__ __align__(16) float xr[16 * 64];   // 4 KB receiver rows
  __shared__ __align__(16) float xc[64 * 68];   // 17.4 KB candidate chunk
  for (int k = t; k < 512; k += 256) { sqs[k] = sq[b * 512 + k]; vls[k] = vlist[b * 512 + k]; }
  __syncthreads();
  const float* xb = x + (size_t)b * 512 * 64;
  {  // stage 16 receiver rows: 16 threads per row
    const int r = t >> 4, f4 = (t & 15) * 4;
    const int slot = tile * 16 + r;
    const int row = vls[slot < nv ? slot : 0];
    *(float4*)(xr + r * 64 + f4) = *(const float4*)(xb + (size_t)row * 64 + f4);
  }
  const int rslot = tile * 16 + w * 4 + i;
  const bool vrow = (rslot < nv);
  const int nrow = vls[rslot < nv ? rslot : 0];
  const float sqn = sqs[nrow];
  __syncthreads();
  const float4 xn = *(const float4*)(xr + (w * 4 + i) * 64 + d * 4);  // once, in regs

  float dotv[32];
#pragma unroll
  for (int j = 0; j < 32; ++j) dotv[j] = 0.f;

#pragma unroll
  for (int cb = 0; cb < 8; ++cb) {
    if (cb * 64 < nv) {  // uniform
      __syncthreads();
      {  // stage 64 candidate rows: 4 float4 per thread
        const int fo = (t & 15) * 4;
#pragma unroll
        for (int p = 0; p < 4; ++p) {
          const int cl = (t >> 4) + p * 16;
          const int c = cb * 64 + cl;
          if (c < nv)
            *(float4*)(xc + cl * 68 + fo) = *(const float4*)(xb + (size_t)vls[c] * 64 + fo);
        }
      }
      __syncthreads();
#pragma unroll
      for (int q = 0; q < 4; ++q) {
        float dq = 0.f;
#pragma unroll 4
        for (int cc = 0; cc < 16; ++cc) {
          const float4 xm = *(const float4*)(xc + (q * 16 + cc) * 68 + d * 4);
          float p = xn.x * xm.x;
          p = fmaf(xn.y, xm.y, p);
          p = fmaf(xn.z, xm.z, p);
          p = fmaf(xn.w, xm.w, p);
          p = rowsum_f32(p);          // full dot, uniform within row
          dq = (d == cc) ? p : dq;    // lane cc keeps candidate q*16+cc
        }
        dotv[cb * 4 + q] = dq;        // static index
      }
    }
  }

  const u64 INF64 = ~0ull;
  u64 s1[16], s2[16];
#pragma unroll
  for (int j = 0; j < 16; ++j) { s1[j] = INF64; s2[j] = INF64; }
#pragma unroll
  for (int j = 0; j < 32; ++j) {
    if (j * 16 < nv) {  // uniform
      const int c = j * 16 + d;
      const int m = vls[c < nv ? c : 0];
      const float dd = fabsf(sqn + sqs[m] - 2.f * dotv[j]);
      const u64 key = (((u64)__float_as_uint(dd)) << 32) | (unsigned)m;
      const bool ok = (c < nv) && (m != nrow);
      if (j < 16) s1[j] = ok ? key : INF64;
      else        s2[j - 16] = ok ? key : INF64;
    }
  }
  bitonic16(s1);
  const bool two = (nv > 256);  // uniform
  if (two) bitonic16(s2);

  int res = nrow;
#pragma unroll
  for (int ts = 0; ts < 16; ++ts) {
    const u64 head = two ? u64min(s1[0], s2[0]) : s1[0];
    const u64 wmin = rowmin_u64(head);
    if (d == ts) res = (wmin == INF64) ? nrow : (int)(unsigned)(wmin & 0xffffffffull);
    const bool w1 = (wmin != INF64) && (s1[0] == wmin);
#pragma unroll
    for (int k = 0; k < 15; ++k) s1[k] = w1 ? s1[k + 1] : s1[k];
    s1[15] = w1 ? INF64 : s1[15];
    if (two) {
      const bool w2 = (wmin != INF64) && (s2[0] == wmin);
#pragma unroll
      for (int k = 0; k < 15; ++k) s2[k] = w2 ? s2[k + 1] : s2[k];
      s2[15] = w2 ? INF64 : s2[15];
    }
  }
  if (vrow) idxg[((size_t)b * 512 + nrow) * 16 + d] = res;
}

// ---------------- Kernel C: edge MLP, BARRIER-FREE, weights direct from L2 ---------
// No LDS weight staging: bfv B-frags load straight from W1p/W2p (96 KB total,
// L2-resident, coalesced 1 KB/wave-instr). LDS = hfrag only (32 KB, wave-private)
// -> zero __syncthreads, 4 blocks/CU. L1 iterates the 4 UNIQUE W1 slabs and fires
// hi+lo MFMAs per bfv (halves W1 reads). fp32 acc-order change only.
__global__ void __launch_bounds__(256) kedge(const bf16_t* __restrict__ xhi,
    const bf16_t* __restrict__ xlo, const int* __restrict__ idxg,
    const int* __restrict__ vlist, const int* __restrict__ vcnt,
    const bf16_t* __restrict__ W1p, const bf16_t* __restrict__ W2p,
    const float* __restrict__ be1, const float* __restrict__ be2,
    float* __restrict__ pooled) {
  const int bb = blockIdx.x >> 6, tile = blockIdx.x & 63;
  const int nv = vcnt[bb];
  if (tile * 8 >= nv) return;
  __shared__ __align__(16) bf16_t hfrag[4][2][2048];   // 32 KB, wave-private
  const int t = threadIdx.x, lane = t & 63, w = t >> 6;
  const int q = lane >> 4, e = lane & 15;

  int gid[2]; bool act[2]; int sv[2];
#pragma unroll
  for (int u = 0; u < 2; ++u) {
    const int slot = tile * 8 + w * 2 + u;
    act[u] = (slot < nv);
    gid[u] = act[u] ? (bb * 512 + vlist[bb * 512 + slot]) : 0;
    sv[u] = act[u] ? idxg[(size_t)gid[u] * 16 + e] : 0;
  }

  f32x4 acc[2][8];
#pragma unroll
  for (int u = 0; u < 2; ++u)
#pragma unroll
    for (int nt = 0; nt < 8; ++nt) acc[u][nt] = zero4();

  // ---- Layer 1: 4 unique W1 slabs; each bfv drives hi- and lo-plane MFMAs ----
#pragma unroll
  for (int sr = 0; sr < 4; ++sr) {
    const int half = sr >> 1, inner = sr & 1;
    bf16x8 afh[2], afl[2];
#pragma unroll
    for (int u = 0; u < 2; ++u) {
      if (act[u]) {
        const int row = half ? (bb * 512 + sv[u]) : gid[u];
        afh[u] = *(const bf16x8*)(xhi + (size_t)row * 64 + inner * 32 + q * 8);
        afl[u] = *(const bf16x8*)(xlo + (size_t)row * 64 + inner * 32 + q * 8);
      }
    }
#pragma unroll
    for (int nt = 0; nt < 8; ++nt) {
      const bf16x8 bfv = *(const bf16x8*)(W1p + (size_t)sr * 4096 + (nt * 64 + lane) * 8);
#pragma unroll
      for (int u = 0; u < 2; ++u) {
        if (act[u]) {
          acc[u][nt] = __builtin_amdgcn_mfma_f32_16x16x32_bf16(afh[u], bfv, acc[u][nt], 0, 0, 0);
          acc[u][nt] = __builtin_amdgcn_mfma_f32_16x16x32_bf16(afl[u], bfv, acc[u][nt], 0, 0, 0);
        }
      }
    }
  }

  // ---- Epilogue 1: bias+relu -> bf16 -> wave-private A-frag buffer ----
#pragma unroll
  for (int u = 0; u < 2; ++u) {
    if (act[u]) {
#pragma unroll
      for (int nt = 0; nt < 8; ++nt) {
        const int cc = nt * 16 + e;
        const float bv = be1[cc];
        const int base = ((cc >> 5) * 64 + (q * 4) + 16 * ((cc >> 3) & 3)) * 8 + (cc & 7);
#pragma unroll
        for (int r = 0; r < 4; ++r) {
          float h = fmaxf(acc[u][nt][r] + bv, 0.f);
          hfrag[w][u][base + r * 8] = f2b(h);
        }
      }
    }
  }
#pragma unroll
  for (int u = 0; u < 2; ++u)
#pragma unroll
    for (int nt = 0; nt < 8; ++nt) acc[u][nt] = zero4();

  // ---- Layer 2: 8 W2 slabs (hi 0-3, lo 4-7), A from hfrag ----
#pragma unroll
  for (int s = 0; s < 8; ++s) {
    const int f = s & 3;
    bf16x8 af[2];
#pragma unroll
    for (int u = 0; u < 2; ++u)
      if (act[u]) af[u] = *(const bf16x8*)(&hfrag[w][u][(f * 64 + lane) * 8]);
#pragma unroll
    for (int nt = 0; nt < 8; ++nt) {
      const bf16x8 bfv = *(const bf16x8*)(W2p + (size_t)s * 4096 + (nt * 64 + lane) * 8);
#pragma unroll
      for (int u = 0; u < 2; ++u)
        if (act[u]) acc[u][nt] = __builtin_amdgcn_mfma_f32_16x16x32_bf16(af[u], bfv, acc[u][nt], 0, 0, 0);
    }
  }

  // ---- Epilogue 2: bias+relu, mean over 16 edges (cnt==16 exactly) ----
#pragma unroll
  for (int u = 0; u < 2; ++u) {
    if (act[u]) {
#pragma unroll
      for (int nt = 0; nt < 8; ++nt) {
        const float bv = be2[nt * 16 + e];
        float part = 0.f;
#pragma unroll
        for (int r = 0; r < 4; ++r) part += fmaxf(acc[u][nt][r] + bv, 0.f);
        part += __shfl_xor(part, 16, 64);
        part += __shfl_xor(part, 32, 64);
        if (lane < 16) pooled[(size_t)gid[u] * 128 + nt * 16 + lane] = part * 0.0625f;
      }
    }
  }
}

// ---------------- Kernel D: node MLP, BARRIER-FREE, weights direct from L2 ---------
// 128-thread blocks (2 waves), grid 512 -> 2+ blocks/CU (was 1). No LDS staging;
// hi/lo A-planes built from ONE float8 read per (u,sr). Zero __syncthreads.
__global__ void __launch_bounds__(128) knode(const float* __restrict__ x,
    const float* __restrict__ pooled, const int* __restrict__ mask,
    const bf16_t* __restrict__ Wn1p, const bf16_t* __restrict__ Wn2p,
    const float* __restrict__ bn1, const float* __restrict__ bn2,
    float* __restrict__ out) {
  __shared__ __align__(16) bf16_t hfrag[2][2][2048];   // 16 KB, wave-private
  const int t = threadIdx.x, lane = t & 63, w = t >> 6;  // w in 0..1
  const int q = lane >> 4, e = lane & 15;
  int nodebase[2];
#pragma unroll
  for (int u = 0; u < 2; ++u) nodebase[u] = (blockIdx.x * 4 + w * 2 + u) * 16;

  f32x4 acc[2][8];
#pragma unroll
  for (int u = 0; u < 2; ++u)
#pragma unroll
    for (int nt = 0; nt < 8; ++nt) acc[u][nt] = zero4();

  // ---- Layer 1: 6 unique Wn1 slabs; hi+lo from one float8 read ----
#pragma unroll
  for (int sr = 0; sr < 6; ++sr) {
    const int col = sr * 32 + q * 8;  // [0,192)
    bf16x8 afh[2], afl[2];
#pragma unroll
    for (int u = 0; u < 2; ++u) {
      const int node = nodebase[u] + e;
      const float* p = (col < 64) ? (x + (size_t)node * 64 + col)
                                  : (pooled + (size_t)node * 128 + (col - 64));
      float4 v0 = *(const float4*)p;
      float4 v1 = *(const float4*)(p + 4);
      float vv[8] = {v0.x, v0.y, v0.z, v0.w, v1.x, v1.y, v1.z, v1.w};
#pragma unroll
      for (int j = 0; j < 8; ++j) {
        bf16_t hi = f2b(vv[j]);
        afh[u][j] = hi;
        afl[u][j] = f2b(vv[j] - b2f(hi));
      }
    }
#pragma unroll
    for (int nt = 0; nt < 8; ++nt) {
      const bf16x8 bfv = *(const bf16x8*)(Wn1p + (size_t)sr * 4096 + (nt * 64 + lane) * 8);
#pragma unroll
      for (int u = 0; u < 2; ++u) {
        acc[u][nt] = __builtin_amdgcn_mfma_f32_16x16x32_bf16(afh[u], bfv, acc[u][nt], 0, 0, 0);
        acc[u][nt] = __builtin_amdgcn_mfma_f32_16x16x32_bf16(afl[u], bfv, acc[u][nt], 0, 0, 0);
      }
    }
  }

  // ---- Epilogue 1 (wave-private hfrag, no barrier) ----
#pragma unroll
  for (int u = 0; u < 2; ++u) {
#pragma unroll
    for (int nt = 0; nt < 8; ++nt) {
      const int cc = nt * 16 + e;
      const float bv = bn1[cc];
      const int base = ((cc >> 5) * 64 + (q * 4) + 16 * ((cc >> 3) & 3)) * 8 + (cc & 7);
#pragma unroll
      for (int r = 0; r < 4; ++r) {
        float h = fmaxf(acc[u][nt][r] + bv, 0.f);
        hfrag[w][u][base + r * 8] = f2b(h);
      }
    }
  }

  // ---- Layer 2: 8 Wn2 slabs (hi 0-3, lo 4-7), A from hfrag ----
  f32x4 acc2[2][4];
#pragma unroll
  for (int u = 0; u < 2; ++u)
#pragma unroll
    for (int nt = 0; nt < 4; ++nt) acc2[u][nt] = zero4();

#pragma unroll
  for (int s = 0; s < 8; ++s) {
    const int f = s & 3;
    bf16x8 af[2];
#pragma unroll
    for (int u = 0; u < 2; ++u)
      af[u] = *(const bf16x8*)(&hfrag[w][u][(f * 64 + lane) * 8]);
#pragma unroll
    for (int nt = 0; nt < 4; ++nt) {
      const bf16x8 bfv = *(const bf16x8*)(Wn2p + (size_t)s * 2048 + (nt * 64 + lane) * 8);
#pragma unroll
      for (int u = 0; u < 2; ++u)
        acc2[u][nt] = __builtin_amdgcn_mfma_f32_16x16x32_bf16(af[u], bfv, acc2[u][nt], 0, 0, 0);
    }
  }

  // ---- Final: + bn2, * mask, store ----
#pragma unroll
  for (int u = 0; u < 2; ++u) {
    int mm[4];
#pragma unroll
    for (int r = 0; r < 4; ++r) mm[r] = mask[nodebase[u] + q * 4 + r];
#pragma unroll
    for (int nt = 0; nt < 4; ++nt) {
      const float bv = bn2[nt * 16 + e];
#pragma unroll
      for (int r = 0; r < 4; ++r) {
        const int node = nodebase[u] + q * 4 + r;
        out[(size_t)node * 64 + nt * 16 + e] = (acc2[u][nt][r] + bv) * (float)mm[r];
      }
    }
  }
}

// ---------------- Launch ----------------
extern "C" void kernel_launch(void* const* d_in, const int* in_sizes, int n_in,
                              void* d_out, int out_size, void* d_ws, size_t ws_size,
                              hipStream_t stream) {
  const float* nodes = (const float*)d_in[0];
  const int*   mask  = (const int*)d_in[1];
  const float* We1   = (const float*)d_in[2];
  const float* be1   = (const float*)d_in[3];
  const float* We2   = (const float*)d_in[4];
  const float* be2   = (const float*)d_in[5];
  const float* Wn1   = (const float*)d_in[6];
  const float* bn1   = (const float*)d_in[7];
  const float* Wn2   = (const float*)d_in[8];
  const float* bn2   = (const float*)d_in[9];
  float* out = (float*)d_out;

  char* p = (char*)d_ws;
  auto alloc = [&](size_t bytes) -> char* {
    char* r = p;
    p += (bytes + 255) & ~(size_t)255;
    return r;
  };
  float*  x      = (float*)alloc((size_t)32768 * 64 * 4);
  bf16_t* xhi    = (bf16_t*)alloc((size_t)32768 * 64 * 2);
  bf16_t* xlo    = (bf16_t*)alloc((size_t)32768 * 64 * 2);
  float*  sq     = (float*)alloc((size_t)32768 * 4);
  int*    vlist  = (int*)alloc((size_t)32768 * 4);
  int*    vcnt   = (int*)alloc((size_t)64 * 4);
  int*    idxg   = (int*)alloc((size_t)32768 * 16 * 4);
  float*  pooled = (float*)alloc((size_t)32768 * 128 * 4);
  bf16_t* W1p    = (bf16_t*)alloc((size_t)8 * 8 * 64 * 8 * 2);
  bf16_t* W2p    = (bf16_t*)alloc((size_t)8 * 8 * 64 * 8 * 2);
  bf16_t* Wn1p   = (bf16_t*)alloc((size_t)12 * 8 * 64 * 8 * 2);
  bf16_t* Wn2p   = (bf16_t*)alloc((size_t)8 * 4 * 64 * 8 * 2);
  if ((size_t)(p - (char*)d_ws) > ws_size) return;  // workspace too small -> loud failure

  kpack<<<64, 256, 0, stream>>>(We1, We2, Wn1, Wn2, W1p, W2p, Wn1p, Wn2p);
  kprep<<<64, 256, 0, stream>>>(nodes, mask, x, xhi, xlo, sq, vlist, vcnt);
  kknn<<<2048, 256, 0, stream>>>(x, sq, vlist, vcnt, idxg);
  kedge<<<4096, 256, 0, stream>>>(xhi, xlo, idxg, vlist, vcnt, W1p, W2p, be1, be2, pooled);
  knode<<<512, 128, 0, stream>>>(x, pooled, mask, Wn1p, Wn2p, bn1, bn2, out);
}

// Round 13
// 245.302 us; speedup vs baseline: 1.2776x; 1.2776x over previous
//
#include <hip/hip_runtime.h>

#define DI __device__ __forceinline__

typedef __bf16 bf16_t;
typedef __bf16 bf16x4 __attribute__((ext_vector_type(4)));
typedef __bf16 bf16x8 __attribute__((ext_vector_type(8)));
typedef float f32x4 __attribute__((ext_vector_type(4)));
typedef unsigned long long u64;

// Problem constants
// B=64, N=512, F=64, H=128, FO=64, K=16

DI bf16_t f2b(float f) {
  unsigned u = __float_as_uint(f);
  unsigned r = (u + 0x7fffu + ((u >> 16) & 1u)) >> 16;
  return __builtin_bit_cast(bf16_t, (unsigned short)r);
}
DI float b2f(bf16_t h) {
  return __uint_as_float(((unsigned)__builtin_bit_cast(unsigned short, h)) << 16);
}
DI f32x4 zero4() { f32x4 z = {0.f, 0.f, 0.f, 0.f}; return z; }

DI bf16x8 make_frag(const float* p, bool wantlo) {
  float4 v0 = *(const float4*)p;
  float4 v1 = *(const float4*)(p + 4);
  float vv[8] = {v0.x, v0.y, v0.z, v0.w, v1.x, v1.y, v1.z, v1.w};
  bf16x8 a;
#pragma unroll
  for (int j = 0; j < 8; ++j) {
    bf16_t hi = f2b(vv[j]);
    a[j] = wantlo ? f2b(vv[j] - b2f(hi)) : hi;
  }
  return a;
}

DI u64 u64min(u64 a, u64 b) { return a < b ? a : b; }
// ctrl must be an ICE for __builtin_amdgcn_update_dpp -> template parameter.
template <int CTRL>
DI u64 dpp_u64(u64 v) {
  int lo = (int)(unsigned)(v & 0xffffffffull);
  int hi = (int)(unsigned)(v >> 32);
  int tlo = __builtin_amdgcn_update_dpp(0, lo, CTRL, 0xF, 0xF, true);
  int thi = __builtin_amdgcn_update_dpp(0, hi, CTRL, 0xF, 0xF, true);
  return (((u64)(unsigned)thi) << 32) | (unsigned)tlo;
}
template <int CTRL>
DI float dpp_f32(float v) {
  int t = __builtin_amdgcn_update_dpp(0, (int)__float_as_uint(v), CTRL, 0xF, 0xF, true);
  return __uint_as_float((unsigned)t);
}
// Min over each 16-lane row; result uniform within the row.
DI u64 rowmin_u64(u64 v) {
  v = u64min(v, dpp_u64<0xB1>(v));
  v = u64min(v, dpp_u64<0x4E>(v));
  v = u64min(v, dpp_u64<0x141>(v));
  v = u64min(v, dpp_u64<0x140>(v));
  return v;
}
// Sum over each 16-lane row (butterfly); result uniform within the row.
DI float rowsum_f32(float v) {
  v += dpp_f32<0xB1>(v);
  v += dpp_f32<0x4E>(v);
  v += dpp_f32<0x141>(v);
  v += dpp_f32<0x140>(v);
  return v;
}
// Bitonic sort, 16 elements, ascending. 80 CAS, all indices compile-time.
DI void bitonic16(u64* a) {
#pragma unroll
  for (int k = 2; k <= 16; k <<= 1)
#pragma unroll
    for (int j = k >> 1; j > 0; j >>= 1)
#pragma unroll
      for (int i = 0; i < 16; ++i) {
        const int l = i ^ j;
        if (l > i) {
          const bool up = ((i & k) == 0);
          const bool sw = up ? (a[i] > a[l]) : (a[i] < a[l]);
          const u64 t0 = a[i], t1 = a[l];
          a[i] = sw ? t1 : t0;
          a[l] = sw ? t0 : t1;
        }
      }
}

// ---------------- Kernel F: fused prep — xplanes (512) + compact (64) + pack (64) --
// blocks 0..511:   x = nodes*m, xhi/xlo split planes, sq (64-node segments, 8/batch)
// blocks 512..575: per-batch valid-index compaction (mask only)
// blocks 576..639: weight packing into split-bf16 MFMA B-fragment layout
__global__ void __launch_bounds__(256) kfuse(const float* __restrict__ nodes,
    const int* __restrict__ mask,
    const float* __restrict__ We1, const float* __restrict__ We2,
    const float* __restrict__ Wn1, const float* __restrict__ Wn2,
    float* __restrict__ x, bf16_t* __restrict__ xhi, bf16_t* __restrict__ xlo,
    float* __restrict__ sq, int* __restrict__ vlist, int* __restrict__ vcnt,
    bf16_t* __restrict__ W1p, bf16_t* __restrict__ W2p,
    bf16_t* __restrict__ Wn1p, bf16_t* __restrict__ Wn2p) {
  const int blk = blockIdx.x, t = threadIdx.x;
  __shared__ int cnts[8];
  __shared__ int basep[8];

  if (blk < 512) {
    // ---- xplanes: batch b, nodes n0..n0+63; 16 threads per row ----
    const int b = blk >> 3, n0 = (blk & 7) * 64;
#pragma unroll
    for (int i = 0; i < 4; ++i) {
      const int idx = t + 256 * i;
      const int gi = b * 512 + n0 + (idx >> 4);
      const int fo = (idx & 15) * 4;
      const float fm = (float)mask[gi];
      const size_t ro = (size_t)gi * 64;
      float4 v = *(const float4*)(nodes + ro + fo);
      v.x *= fm; v.y *= fm; v.z *= fm; v.w *= fm;
      *(float4*)(x + ro + fo) = v;
      float vv[4] = {v.x, v.y, v.z, v.w};
      bf16x4 hh, ll;
#pragma unroll
      for (int k = 0; k < 4; ++k) {
        bf16_t hi = f2b(vv[k]);
        hh[k] = hi;
        ll[k] = f2b(vv[k] - b2f(hi));
      }
      *(bf16x4*)(xhi + ro + fo) = hh;
      *(bf16x4*)(xlo + ro + fo) = ll;
      float s = v.x * v.x + v.y * v.y + v.z * v.z + v.w * v.w;
      s = rowsum_f32(s);  // sum over the row's 16 lanes (uniform in row)
      if ((t & 15) == 0) sq[gi] = s;
    }
  } else if (blk < 576) {
    // ---- compaction: one block per batch ----
    const int b = blk - 512, lane = t & 63, w = t >> 6;
    unsigned long long bal[2]; int flag[2];
#pragma unroll
    for (int h = 0; h < 2; ++h) {
      flag[h] = (mask[b * 512 + h * 256 + t] != 0);
      bal[h] = __ballot(flag[h]);
      if (lane == 0) cnts[h * 4 + w] = __popcll(bal[h]);
    }
    __syncthreads();
    if (t == 0) {
      int a = 0;
      for (int c = 0; c < 8; ++c) { basep[c] = a; a += cnts[c]; }
      vcnt[b] = a;
    }
    __syncthreads();
#pragma unroll
    for (int h = 0; h < 2; ++h) {
      if (flag[h]) {
        const unsigned long long lt = (lane == 0) ? 0ull : (~0ull >> (64 - lane));
        const int pos = basep[h * 4 + w] + __popcll(bal[h] & lt);
        vlist[b * 512 + pos] = h * 256 + t;
      }
    }
  } else {
    // ---- weight pack ----
    int p = (blk - 576) * 256 + t;  // 0..16383
    const float* W; bf16_t* dst; int K, Nn, local, mode;
    if (p < 4096)       { W = We1; dst = W1p;  K = 128; Nn = 128; mode = 0; local = p; }
    else if (p < 8192)  { W = We2; dst = W2p;  K = 128; Nn = 128; mode = 1; local = p - 4096; }
    else if (p < 14336) { W = Wn1; dst = Wn1p; K = 192; Nn = 128; mode = 0; local = p - 8192; }
    else                { W = Wn2; dst = Wn2p; K = 128; Nn = 64;  mode = 1; local = p - 14336; }
    int lane = local & 63;
    int nnt = (Nn >> 4);
    int chunk = local >> 6;
    int nt = chunk % nnt;
    int s = chunk / nnt;
    int n = nt * 16 + (lane & 15);
    int kbase = s * 32 + ((lane >> 4) * 8);
    bf16x8 v;
#pragma unroll
    for (int j = 0; j < 8; ++j) {
      int kp = kbase + j;
      int region = kp / K;
      int kk = kp - region * K;
      float w = W[kk * Nn + n];
      bf16_t hi = f2b(w);
      v[j] = (mode == 1 && region == 1) ? f2b(w - b2f(hi)) : hi;
    }
    *(bf16x8*)(dst + (size_t)local * 8) = v;
  }
}

// ---------------- Kernel B: distances + top-16 (self excluded), row-parallel -------
// (unchanged from r8)
__global__ void __launch_bounds__(256) kknn(const float* __restrict__ x,
    const float* __restrict__ sq, const int* __restrict__ vlist,
    const int* __restrict__ vcnt, int* __restrict__ idxg) {
  const int b = blockIdx.x & 63, tile = blockIdx.x >> 6;
  const int nv = vcnt[b];
  if (tile * 16 >= nv) return;  // block-uniform, before any barrier
  const int t = threadIdx.x, lane = t & 63, w = t >> 6;
  const int i = lane >> 4, d = lane & 15;
  __shared__ float sqs[512];
  __shared__ int vls[512];
  __shared__ __align__(16) float xr[16 * 64];   // 4 KB receiver rows
  __shared__ __align__(16) float xc[64 * 68];   // 17.4 KB candidate chunk
  for (int k = t; k < 512; k += 256) { sqs[k] = sq[b * 512 + k]; vls[k] = vlist[b * 512 + k]; }
  __syncthreads();
  const float* xb = x + (size_t)b * 512 * 64;
  {  // stage 16 receiver rows: 16 threads per row
    const int r = t >> 4, f4 = (t & 15) * 4;
    const int slot = tile * 16 + r;
    const int row = vls[slot < nv ? slot : 0];
    *(float4*)(xr + r * 64 + f4) = *(const float4*)(xb + (size_t)row * 64 + f4);
  }
  const int rslot = tile * 16 + w * 4 + i;
  const bool vrow = (rslot < nv);
  const int nrow = vls[rslot < nv ? rslot : 0];
  const float sqn = sqs[nrow];
  __syncthreads();
  const float4 xn = *(const float4*)(xr + (w * 4 + i) * 64 + d * 4);  // once, in regs

  float dotv[32];
#pragma unroll
  for (int j = 0; j < 32; ++j) dotv[j] = 0.f;

#pragma unroll
  for (int cb = 0; cb < 8; ++cb) {
    if (cb * 64 < nv) {  // uniform
      __syncthreads();
      {  // stage 64 candidate rows: 4 float4 per thread
        const int fo = (t & 15) * 4;
#pragma unroll
        for (int p = 0; p < 4; ++p) {
          const int cl = (t >> 4) + p * 16;
          const int c = cb * 64 + cl;
          if (c < nv)
            *(float4*)(xc + cl * 68 + fo) = *(const float4*)(xb + (size_t)vls[c] * 64 + fo);
        }
      }
      __syncthreads();
#pragma unroll
      for (int q = 0; q < 4; ++q) {
        float dq = 0.f;
#pragma unroll 4
        for (int cc = 0; cc < 16; ++cc) {
          const float4 xm = *(const float4*)(xc + (q * 16 + cc) * 68 + d * 4);
          float p = xn.x * xm.x;
          p = fmaf(xn.y, xm.y, p);
          p = fmaf(xn.z, xm.z, p);
          p = fmaf(xn.w, xm.w, p);
          p = rowsum_f32(p);          // full dot, uniform within row
          dq = (d == cc) ? p : dq;    // lane cc keeps candidate q*16+cc
        }
        dotv[cb * 4 + q] = dq;        // static index
      }
    }
  }

  const u64 INF64 = ~0ull;
  u64 s1[16], s2[16];
#pragma unroll
  for (int j = 0; j < 16; ++j) { s1[j] = INF64; s2[j] = INF64; }
#pragma unroll
  for (int j = 0; j < 32; ++j) {
    if (j * 16 < nv) {  // uniform
      const int c = j * 16 + d;
      const int m = vls[c < nv ? c : 0];
      const float dd = fabsf(sqn + sqs[m] - 2.f * dotv[j]);
      const u64 key = (((u64)__float_as_uint(dd)) << 32) | (unsigned)m;
      const bool ok = (c < nv) && (m != nrow);
      if (j < 16) s1[j] = ok ? key : INF64;
      else        s2[j - 16] = ok ? key : INF64;
    }
  }
  bitonic16(s1);
  const bool two = (nv > 256);  // uniform
  if (two) bitonic16(s2);

  int res = nrow;
#pragma unroll
  for (int ts = 0; ts < 16; ++ts) {
    const u64 head = two ? u64min(s1[0], s2[0]) : s1[0];
    const u64 wmin = rowmin_u64(head);
    if (d == ts) res = (wmin == INF64) ? nrow : (int)(unsigned)(wmin & 0xffffffffull);
    const bool w1 = (wmin != INF64) && (s1[0] == wmin);
#pragma unroll
    for (int k = 0; k < 15; ++k) s1[k] = w1 ? s1[k + 1] : s1[k];
    s1[15] = w1 ? INF64 : s1[15];
    if (two) {
      const bool w2 = (wmin != INF64) && (s2[0] == wmin);
#pragma unroll
      for (int k = 0; k < 15; ++k) s2[k] = w2 ? s2[k + 1] : s2[k];
      s2[15] = w2 ? INF64 : s2[15];
    }
  }
  if (vrow) idxg[((size_t)b * 512 + nrow) * 16 + d] = res;
}

// ---------------- Kernel C: edge MLP — EXACT R8 structure (95 us proven) -----------
// 16 KB phases (2 slabs per barrier pair), inline A-frag loads, 3 blocks/CU.
// Measured ranking of 5 structural variants: this beats 12-barrier (117), reg-dbuf
// (166), 5-barrier monolithic (113), and barrier-free L2-direct (139).
__global__ void __launch_bounds__(256) kedge(const bf16_t* __restrict__ xhi,
    const bf16_t* __restrict__ xlo, const int* __restrict__ idxg,
    const int* __restrict__ vlist, const int* __restrict__ vcnt,
    const bf16_t* __restrict__ W1p, const bf16_t* __restrict__ W2p,
    const float* __restrict__ be1, const float* __restrict__ be2,
    float* __restrict__ pooled) {
  const int bb = blockIdx.x >> 6, tile = blockIdx.x & 63;
  const int nv = vcnt[bb];
  if (tile * 8 >= nv) return;  // block-uniform, before any barrier
  __shared__ __align__(16) bf16_t wbuf[8192];          // 16 KB: 2 slabs per phase
  __shared__ __align__(16) bf16_t hfrag[4][2][2048];   // 32 KB
  const int t = threadIdx.x, lane = t & 63, w = t >> 6;
  const int q = lane >> 4, e = lane & 15;

  int gid[2]; bool act[2]; int sv[2];
#pragma unroll
  for (int u = 0; u < 2; ++u) {
    const int slot = tile * 8 + w * 2 + u;
    act[u] = (slot < nv);
    gid[u] = act[u] ? (bb * 512 + vlist[bb * 512 + slot]) : 0;
    sv[u] = act[u] ? idxg[(size_t)gid[u] * 16 + e] : 0;
  }

  f32x4 acc[2][8];
#pragma unroll
  for (int u = 0; u < 2; ++u)
#pragma unroll
    for (int nt = 0; nt < 8; ++nt) acc[u][nt] = zero4();

  // ---- Layer 1: 4 phases x 2 slabs ----
  for (int p = 0; p < 4; ++p) {
    __syncthreads();
    {
      const uint4* src = (const uint4*)(W1p + (size_t)p * 8192);
      uint4* dst = (uint4*)wbuf;
#pragma unroll
      for (int i = 0; i < 4; ++i) dst[t + 256 * i] = src[t + 256 * i];
    }
    __syncthreads();
#pragma unroll
    for (int sl = 0; sl < 2; ++sl) {
      const int s = p * 2 + sl;
      const bool wantlo = (s >= 4);
      const int sr = s & 3, half = sr >> 1, inner = sr & 1;
      const int col = inner * 32 + q * 8;
      const bf16_t* plane = wantlo ? xlo : xhi;
      bf16x8 af[2];
#pragma unroll
      for (int u = 0; u < 2; ++u) {
        if (act[u]) {
          const int row = half ? (bb * 512 + sv[u]) : gid[u];
          af[u] = *(const bf16x8*)(plane + (size_t)row * 64 + col);
        }
      }
#pragma unroll
      for (int nt = 0; nt < 8; ++nt) {
        const bf16x8 bfv = *(const bf16x8*)(wbuf + sl * 4096 + (nt * 64 + lane) * 8);
#pragma unroll
        for (int u = 0; u < 2; ++u)
          if (act[u]) acc[u][nt] = __builtin_amdgcn_mfma_f32_16x16x32_bf16(af[u], bfv, acc[u][nt], 0, 0, 0);
      }
    }
  }

  // ---- Epilogue 1: bias+relu -> bf16 hi -> per-wave lane-linear A-frag buffer ----
#pragma unroll
  for (int u = 0; u < 2; ++u) {
    if (act[u]) {
#pragma unroll
      for (int nt = 0; nt < 8; ++nt) {
        const int cc = nt * 16 + e;
        const float bv = be1[cc];
        const int base = ((cc >> 5) * 64 + (q * 4) + 16 * ((cc >> 3) & 3)) * 8 + (cc & 7);
#pragma unroll
        for (int r = 0; r < 4; ++r) {
          float h = fmaxf(acc[u][nt][r] + bv, 0.f);
          hfrag[w][u][base + r * 8] = f2b(h);
        }
      }
    }
  }

  // ---- Layer 2: 4 phases x 2 slabs ----
#pragma unroll
  for (int u = 0; u < 2; ++u)
#pragma unroll
    for (int nt = 0; nt < 8; ++nt) acc[u][nt] = zero4();

  for (int p = 0; p < 4; ++p) {
    __syncthreads();
    {
      const uint4* src = (const uint4*)(W2p + (size_t)p * 8192);
      uint4* dst = (uint4*)wbuf;
#pragma unroll
      for (int i = 0; i < 4; ++i) dst[t + 256 * i] = src[t + 256 * i];
    }
    __syncthreads();
#pragma unroll
    for (int sl = 0; sl < 2; ++sl) {
      const int s = p * 2 + sl;
      const int f = s & 3;
      bf16x8 af[2];
#pragma unroll
      for (int u = 0; u < 2; ++u)
        if (act[u]) af[u] = *(const bf16x8*)(&hfrag[w][u][(f * 64 + lane) * 8]);
#pragma unroll
      for (int nt = 0; nt < 8; ++nt) {
        const bf16x8 bfv = *(const bf16x8*)(wbuf + sl * 4096 + (nt * 64 + lane) * 8);
#pragma unroll
        for (int u = 0; u < 2; ++u)
          if (act[u]) acc[u][nt] = __builtin_amdgcn_mfma_f32_16x16x32_bf16(af[u], bfv, acc[u][nt], 0, 0, 0);
      }
    }
  }

  // ---- Epilogue 2: bias+relu, mean over 16 edges (cnt==16 exactly) ----
#pragma unroll
  for (int u = 0; u < 2; ++u) {
    if (act[u]) {
#pragma unroll
      for (int nt = 0; nt < 8; ++nt) {
        const float bv = be2[nt * 16 + e];
        float part = 0.f;
#pragma unroll
        for (int r = 0; r < 4; ++r) part += fmaxf(acc[u][nt][r] + bv, 0.f);
        part += __shfl_xor(part, 16, 64);
        part += __shfl_xor(part, 32, 64);
        if (lane < 16) pooled[(size_t)gid[u] * 128 + nt * 16 + lane] = part * 0.0625f;
      }
    }
  }
}

// ---------------- Kernel D: node MLP, few-phase staging (r9 version — proven) ------
__global__ void __launch_bounds__(256) knode(const float* __restrict__ x,
    const float* __restrict__ pooled, const int* __restrict__ mask,
    const bf16_t* __restrict__ Wn1p, const bf16_t* __restrict__ Wn2p,
    const float* __restrict__ bn1, const float* __restrict__ bn2,
    float* __restrict__ out) {
  __shared__ __align__(16) bf16_t wbuf[8192];          // 16 KB
  __shared__ __align__(16) bf16_t hfrag[4][2][2048];   // 32 KB
  const int t = threadIdx.x, lane = t & 63, w = t >> 6;
  const int q = lane >> 4, e = lane & 15;
  int nodebase[2];
#pragma unroll
  for (int u = 0; u < 2; ++u) nodebase[u] = (blockIdx.x * 8 + w * 2 + u) * 16;

  f32x4 acc[2][8];
#pragma unroll
  for (int u = 0; u < 2; ++u)
#pragma unroll
    for (int nt = 0; nt < 8; ++nt) acc[u][nt] = zero4();

  // ---- Layer 1: 3 phases x (2 unique slabs, 4 s-iters) ----
#pragma unroll
  for (int ph = 0; ph < 3; ++ph) {
    __syncthreads();
    {
      const uint4* src = (const uint4*)(Wn1p + (size_t)ph * 8192);
      uint4* dst = (uint4*)wbuf;
#pragma unroll
      for (int i = 0; i < 4; ++i) dst[t + 256 * i] = src[t + 256 * i];
    }
    __syncthreads();
#pragma unroll
    for (int k = 0; k < 4; ++k) {
      const int s = 2 * ph + (k & 1) + (k >> 1) * 6;
      const bool wantlo = (s >= 6);
      const int sr = wantlo ? (s - 6) : s;
      const int col = sr * 32 + q * 8;  // [0,192)
      bf16x8 af[2];
#pragma unroll
      for (int u = 0; u < 2; ++u) {
        const int node = nodebase[u] + e;
        const float* p = (col < 64) ? (x + (size_t)node * 64 + col)
                                    : (pooled + (size_t)node * 128 + (col - 64));
        af[u] = make_frag(p, wantlo);
      }
      const int bslab = s & 1;
#pragma unroll
      for (int nt = 0; nt < 8; ++nt) {
        const bf16x8 bfv = *(const bf16x8*)(wbuf + bslab * 4096 + (nt * 64 + lane) * 8);
#pragma unroll
        for (int u = 0; u < 2; ++u)
          acc[u][nt] = __builtin_amdgcn_mfma_f32_16x16x32_bf16(af[u], bfv, acc[u][nt], 0, 0, 0);
      }
    }
  }

  // ---- Epilogue 1 (wave-private hfrag, no barrier) ----
#pragma unroll
  for (int u = 0; u < 2; ++u) {
#pragma unroll
    for (int nt = 0; nt < 8; ++nt) {
      const int cc = nt * 16 + e;
      const float bv = bn1[cc];
      const int base = ((cc >> 5) * 64 + (q * 4) + 16 * ((cc >> 3) & 3)) * 8 + (cc & 7);
#pragma unroll
      for (int r = 0; r < 4; ++r) {
        float h = fmaxf(acc[u][nt][r] + bv, 0.f);
        hfrag[w][u][base + r * 8] = f2b(h);
      }
    }
  }

  // ---- Layer 2: 2 phases x (4 slabs of 2048 elems, 4 s-iters) ----
  f32x4 acc2[2][4];
#pragma unroll
  for (int u = 0; u < 2; ++u)
#pragma unroll
    for (int nt = 0; nt < 4; ++nt) acc2[u][nt] = zero4();

#pragma unroll
  for (int p2 = 0; p2 < 2; ++p2) {
    __syncthreads();
    {
      const uint4* src = (const uint4*)(Wn2p + (size_t)p2 * 8192);
      uint4* dst = (uint4*)wbuf;
#pragma unroll
      for (int i = 0; i < 4; ++i) dst[t + 256 * i] = src[t + 256 * i];
    }
    __syncthreads();
#pragma unroll
    for (int sl = 0; sl < 4; ++sl) {
      const int s = p2 * 4 + sl;
      const int f = s & 3;
      bf16x8 af[2];
#pragma unroll
      for (int u = 0; u < 2; ++u)
        af[u] = *(const bf16x8*)(&hfrag[w][u][(f * 64 + lane) * 8]);
#pragma unroll
      for (int nt = 0; nt < 4; ++nt) {
        const bf16x8 bfv = *(const bf16x8*)(wbuf + sl * 2048 + (nt * 64 + lane) * 8);
#pragma unroll
        for (int u = 0; u < 2; ++u)
          acc2[u][nt] = __builtin_amdgcn_mfma_f32_16x16x32_bf16(af[u], bfv, acc2[u][nt], 0, 0, 0);
      }
    }
  }

  // ---- Final: + bn2, * mask, store ----
#pragma unroll
  for (int u = 0; u < 2; ++u) {
    int mm[4];
#pragma unroll
    for (int r = 0; r < 4; ++r) mm[r] = mask[nodebase[u] + q * 4 + r];
#pragma unroll
    for (int nt = 0; nt < 4; ++nt) {
      const float bv = bn2[nt * 16 + e];
#pragma unroll
      for (int r = 0; r < 4; ++r) {
        const int node = nodebase[u] + q * 4 + r;
        out[(size_t)node * 64 + nt * 16 + e] = (acc2[u][nt][r] + bv) * (float)mm[r];
      }
    }
  }
}

// ---------------- Launch ----------------
extern "C" void kernel_launch(void* const* d_in, const int* in_sizes, int n_in,
                              void* d_out, int out_size, void* d_ws, size_t ws_size,
                              hipStream_t stream) {
  const float* nodes = (const float*)d_in[0];
  const int*   mask  = (const int*)d_in[1];
  const float* We1   = (const float*)d_in[2];
  const float* be1   = (const float*)d_in[3];
  const float* We2   = (const float*)d_in[4];
  const float* be2   = (const float*)d_in[5];
  const float* Wn1   = (const float*)d_in[6];
  const float* bn1   = (const float*)d_in[7];
  const float* Wn2   = (const float*)d_in[8];
  const float* bn2   = (const float*)d_in[9];
  float* out = (float*)d_out;

  char* p = (char*)d_ws;
  auto alloc = [&](size_t bytes) -> char* {
    char* r = p;
    p += (bytes + 255) & ~(size_t)255;
    return r;
  };
  float*  x      = (float*)alloc((size_t)32768 * 64 * 4);
  bf16_t* xhi    = (bf16_t*)alloc((size_t)32768 * 64 * 2);
  bf16_t* xlo    = (bf16_t*)alloc((size_t)32768 * 64 * 2);
  float*  sq     = (float*)alloc((size_t)32768 * 4);
  int*    vlist  = (int*)alloc((size_t)32768 * 4);
  int*    vcnt   = (int*)alloc((size_t)64 * 4);
  int*    idxg   = (int*)alloc((size_t)32768 * 16 * 4);
  float*  pooled = (float*)alloc((size_t)32768 * 128 * 4);
  bf16_t* W1p    = (bf16_t*)alloc((size_t)8 * 8 * 64 * 8 * 2);
  bf16_t* W2p    = (bf16_t*)alloc((size_t)8 * 8 * 64 * 8 * 2);
  bf16_t* Wn1p   = (bf16_t*)alloc((size_t)12 * 8 * 64 * 8 * 2);
  bf16_t* Wn2p   = (bf16_t*)alloc((size_t)8 * 4 * 64 * 8 * 2);
  if ((size_t)(p - (char*)d_ws) > ws_size) return;  // workspace too small -> loud failure

  kfuse<<<640, 256, 0, stream>>>(nodes, mask, We1, We2, Wn1, Wn2,
                                 x, xhi, xlo, sq, vlist, vcnt, W1p, W2p, Wn1p, Wn2p);
  kknn<<<2048, 256, 0, stream>>>(x, sq, vlist, vcnt, idxg);
  kedge<<<4096, 256, 0, stream>>>(xhi, xlo, idxg, vlist, vcnt, W1p, W2p, be1, be2, pooled);
  knode<<<256, 256, 0, stream>>>(x, pooled, mask, Wn1p, Wn2p, bn1, bn2, out);
}

// Round 14
// 226.441 us; speedup vs baseline: 1.3840x; 1.0833x over previous
//
#include <hip/hip_runtime.h>

#define DI __device__ __forceinline__

typedef __bf16 bf16_t;
typedef __bf16 bf16x4 __attribute__((ext_vector_type(4)));
typedef __bf16 bf16x8 __attribute__((ext_vector_type(8)));
typedef float f32x4 __attribute__((ext_vector_type(4)));
typedef unsigned long long u64;

// Problem constants
// B=64, N=512, F=64, H=128, FO=64, K=16

DI bf16_t f2b(float f) {
  unsigned u = __float_as_uint(f);
  unsigned r = (u + 0x7fffu + ((u >> 16) & 1u)) >> 16;
  return __builtin_bit_cast(bf16_t, (unsigned short)r);
}
DI float b2f(bf16_t h) {
  return __uint_as_float(((unsigned)__builtin_bit_cast(unsigned short, h)) << 16);
}
DI f32x4 zero4() { f32x4 z = {0.f, 0.f, 0.f, 0.f}; return z; }

DI bf16x8 make_frag(const float* p, bool wantlo) {
  float4 v0 = *(const float4*)p;
  float4 v1 = *(const float4*)(p + 4);
  float vv[8] = {v0.x, v0.y, v0.z, v0.w, v1.x, v1.y, v1.z, v1.w};
  bf16x8 a;
#pragma unroll
  for (int j = 0; j < 8; ++j) {
    bf16_t hi = f2b(vv[j]);
    a[j] = wantlo ? f2b(vv[j] - b2f(hi)) : hi;
  }
  return a;
}

DI u64 u64min(u64 a, u64 b) { return a < b ? a : b; }
// ctrl must be an ICE for __builtin_amdgcn_update_dpp -> template parameter.
template <int CTRL>
DI u64 dpp_u64(u64 v) {
  int lo = (int)(unsigned)(v & 0xffffffffull);
  int hi = (int)(unsigned)(v >> 32);
  int tlo = __builtin_amdgcn_update_dpp(0, lo, CTRL, 0xF, 0xF, true);
  int thi = __builtin_amdgcn_update_dpp(0, hi, CTRL, 0xF, 0xF, true);
  return (((u64)(unsigned)thi) << 32) | (unsigned)tlo;
}
template <int CTRL>
DI float dpp_f32(float v) {
  int t = __builtin_amdgcn_update_dpp(0, (int)__float_as_uint(v), CTRL, 0xF, 0xF, true);
  return __uint_as_float((unsigned)t);
}
// Min over each 16-lane row; result uniform within the row.
DI u64 rowmin_u64(u64 v) {
  v = u64min(v, dpp_u64<0xB1>(v));
  v = u64min(v, dpp_u64<0x4E>(v));
  v = u64min(v, dpp_u64<0x141>(v));
  v = u64min(v, dpp_u64<0x140>(v));
  return v;
}
// Sum over each 16-lane row (butterfly); result uniform within the row.
DI float rowsum_f32(float v) {
  v += dpp_f32<0xB1>(v);
  v += dpp_f32<0x4E>(v);
  v += dpp_f32<0x141>(v);
  v += dpp_f32<0x140>(v);
  return v;
}
// Bitonic sort, 16 elements, ascending. 80 CAS, all indices compile-time.
DI void bitonic16(u64* a) {
#pragma unroll
  for (int k = 2; k <= 16; k <<= 1)
#pragma unroll
    for (int j = k >> 1; j > 0; j >>= 1)
#pragma unroll
      for (int i = 0; i < 16; ++i) {
        const int l = i ^ j;
        if (l > i) {
          const bool up = ((i & k) == 0);
          const bool sw = up ? (a[i] > a[l]) : (a[i] < a[l]);
          const u64 t0 = a[i], t1 = a[l];
          a[i] = sw ? t1 : t0;
          a[l] = sw ? t0 : t1;
        }
      }
}

// ---------------- Kernel F: fused prep — xplanes (512) + compact (64) + pack (64) --
__global__ void __launch_bounds__(256) kfuse(const float* __restrict__ nodes,
    const int* __restrict__ mask,
    const float* __restrict__ We1, const float* __restrict__ We2,
    const float* __restrict__ Wn1, const float* __restrict__ Wn2,
    float* __restrict__ x, bf16_t* __restrict__ xhi, bf16_t* __restrict__ xlo,
    float* __restrict__ sq, int* __restrict__ vlist, int* __restrict__ vcnt,
    bf16_t* __restrict__ W1p, bf16_t* __restrict__ W2p,
    bf16_t* __restrict__ Wn1p, bf16_t* __restrict__ Wn2p) {
  const int blk = blockIdx.x, t = threadIdx.x;
  __shared__ int cnts[8];
  __shared__ int basep[8];

  if (blk < 512) {
    // ---- xplanes: batch b, nodes n0..n0+63; 16 threads per row ----
    const int b = blk >> 3, n0 = (blk & 7) * 64;
#pragma unroll
    for (int i = 0; i < 4; ++i) {
      const int idx = t + 256 * i;
      const int gi = b * 512 + n0 + (idx >> 4);
      const int fo = (idx & 15) * 4;
      const float fm = (float)mask[gi];
      const size_t ro = (size_t)gi * 64;
      float4 v = *(const float4*)(nodes + ro + fo);
      v.x *= fm; v.y *= fm; v.z *= fm; v.w *= fm;
      *(float4*)(x + ro + fo) = v;
      float vv[4] = {v.x, v.y, v.z, v.w};
      bf16x4 hh, ll;
#pragma unroll
      for (int k = 0; k < 4; ++k) {
        bf16_t hi = f2b(vv[k]);
        hh[k] = hi;
        ll[k] = f2b(vv[k] - b2f(hi));
      }
      *(bf16x4*)(xhi + ro + fo) = hh;
      *(bf16x4*)(xlo + ro + fo) = ll;
      float s = v.x * v.x + v.y * v.y + v.z * v.z + v.w * v.w;
      s = rowsum_f32(s);  // sum over the row's 16 lanes (uniform in row)
      if ((t & 15) == 0) sq[gi] = s;
    }
  } else if (blk < 576) {
    // ---- compaction: one block per batch ----
    const int b = blk - 512, lane = t & 63, w = t >> 6;
    unsigned long long bal[2]; int flag[2];
#pragma unroll
    for (int h = 0; h < 2; ++h) {
      flag[h] = (mask[b * 512 + h * 256 + t] != 0);
      bal[h] = __ballot(flag[h]);
      if (lane == 0) cnts[h * 4 + w] = __popcll(bal[h]);
    }
    __syncthreads();
    if (t == 0) {
      int a = 0;
      for (int c = 0; c < 8; ++c) { basep[c] = a; a += cnts[c]; }
      vcnt[b] = a;
    }
    __syncthreads();
#pragma unroll
    for (int h = 0; h < 2; ++h) {
      if (flag[h]) {
        const unsigned long long lt = (lane == 0) ? 0ull : (~0ull >> (64 - lane));
        const int pos = basep[h * 4 + w] + __popcll(bal[h] & lt);
        vlist[b * 512 + pos] = h * 256 + t;
      }
    }
  } else {
    // ---- weight pack ----
    int p = (blk - 576) * 256 + t;  // 0..16383
    const float* W; bf16_t* dst; int K, Nn, local, mode;
    if (p < 4096)       { W = We1; dst = W1p;  K = 128; Nn = 128; mode = 0; local = p; }
    else if (p < 8192)  { W = We2; dst = W2p;  K = 128; Nn = 128; mode = 1; local = p - 4096; }
    else if (p < 14336) { W = Wn1; dst = Wn1p; K = 192; Nn = 128; mode = 0; local = p - 8192; }
    else                { W = Wn2; dst = Wn2p; K = 128; Nn = 64;  mode = 1; local = p - 14336; }
    int lane = local & 63;
    int nnt = (Nn >> 4);
    int chunk = local >> 6;
    int nt = chunk % nnt;
    int s = chunk / nnt;
    int n = nt * 16 + (lane & 15);
    int kbase = s * 32 + ((lane >> 4) * 8);
    bf16x8 v;
#pragma unroll
    for (int j = 0; j < 8; ++j) {
      int kp = kbase + j;
      int region = kp / K;
      int kk = kp - region * K;
      float w = W[kk * Nn + n];
      bf16_t hi = f2b(w);
      v[j] = (mode == 1 && region == 1) ? f2b(w - b2f(hi)) : hi;
    }
    *(bf16x8*)(dst + (size_t)local * 8) = v;
  }
}

// ---------------- Kernel B: distances + top-16 (self excluded), row-parallel -------
// (unchanged from r8)
__global__ void __launch_bounds__(256) kknn(const float* __restrict__ x,
    const float* __restrict__ sq, const int* __restrict__ vlist,
    const int* __restrict__ vcnt, int* __restrict__ idxg) {
  const int b = blockIdx.x & 63, tile = blockIdx.x >> 6;
  const int nv = vcnt[b];
  if (tile * 16 >= nv) return;  // block-uniform, before any barrier
  const int t = threadIdx.x, lane = t & 63, w = t >> 6;
  const int i = lane >> 4, d = lane & 15;
  __shared__ float sqs[512];
  __shared__ int vls[512];
  __shared__ __align__(16) float xr[16 * 64];   // 4 KB receiver rows
  __shared__ __align__(16) float xc[64 * 68];   // 17.4 KB candidate chunk
  for (int k = t; k < 512; k += 256) { sqs[k] = sq[b * 512 + k]; vls[k] = vlist[b * 512 + k]; }
  __syncthreads();
  const float* xb = x + (size_t)b * 512 * 64;
  {  // stage 16 receiver rows: 16 threads per row
    const int r = t >> 4, f4 = (t & 15) * 4;
    const int slot = tile * 16 + r;
    const int row = vls[slot < nv ? slot : 0];
    *(float4*)(xr + r * 64 + f4) = *(const float4*)(xb + (size_t)row * 64 + f4);
  }
  const int rslot = tile * 16 + w * 4 + i;
  const bool vrow = (rslot < nv);
  const int nrow = vls[rslot < nv ? rslot : 0];
  const float sqn = sqs[nrow];
  __syncthreads();
  const float4 xn = *(const float4*)(xr + (w * 4 + i) * 64 + d * 4);  // once, in regs

  float dotv[32];
#pragma unroll
  for (int j = 0; j < 32; ++j) dotv[j] = 0.f;

#pragma unroll
  for (int cb = 0; cb < 8; ++cb) {
    if (cb * 64 < nv) {  // uniform
      __syncthreads();
      {  // stage 64 candidate rows: 4 float4 per thread
        const int fo = (t & 15) * 4;
#pragma unroll
        for (int p = 0; p < 4; ++p) {
          const int cl = (t >> 4) + p * 16;
          const int c = cb * 64 + cl;
          if (c < nv)
            *(float4*)(xc + cl * 68 + fo) = *(const float4*)(xb + (size_t)vls[c] * 64 + fo);
        }
      }
      __syncthreads();
#pragma unroll
      for (int q = 0; q < 4; ++q) {
        float dq = 0.f;
#pragma unroll 4
        for (int cc = 0; cc < 16; ++cc) {
          const float4 xm = *(const float4*)(xc + (q * 16 + cc) * 68 + d * 4);
          float p = xn.x * xm.x;
          p = fmaf(xn.y, xm.y, p);
          p = fmaf(xn.z, xm.z, p);
          p = fmaf(xn.w, xm.w, p);
          p = rowsum_f32(p);          // full dot, uniform within row
          dq = (d == cc) ? p : dq;    // lane cc keeps candidate q*16+cc
        }
        dotv[cb * 4 + q] = dq;        // static index
      }
    }
  }

  const u64 INF64 = ~0ull;
  u64 s1[16], s2[16];
#pragma unroll
  for (int j = 0; j < 16; ++j) { s1[j] = INF64; s2[j] = INF64; }
#pragma unroll
  for (int j = 0; j < 32; ++j) {
    if (j * 16 < nv) {  // uniform
      const int c = j * 16 + d;
      const int m = vls[c < nv ? c : 0];
      const float dd = fabsf(sqn + sqs[m] - 2.f * dotv[j]);
      const u64 key = (((u64)__float_as_uint(dd)) << 32) | (unsigned)m;
      const bool ok = (c < nv) && (m != nrow);
      if (j < 16) s1[j] = ok ? key : INF64;
      else        s2[j - 16] = ok ? key : INF64;
    }
  }
  bitonic16(s1);
  const bool two = (nv > 256);  // uniform
  if (two) bitonic16(s2);

  int res = nrow;
#pragma unroll
  for (int ts = 0; ts < 16; ++ts) {
    const u64 head = two ? u64min(s1[0], s2[0]) : s1[0];
    const u64 wmin = rowmin_u64(head);
    if (d == ts) res = (wmin == INF64) ? nrow : (int)(unsigned)(wmin & 0xffffffffull);
    const bool w1 = (wmin != INF64) && (s1[0] == wmin);
#pragma unroll
    for (int k = 0; k < 15; ++k) s1[k] = w1 ? s1[k + 1] : s1[k];
    s1[15] = w1 ? INF64 : s1[15];
    if (two) {
      const bool w2 = (wmin != INF64) && (s2[0] == wmin);
#pragma unroll
      for (int k = 0; k < 15; ++k) s2[k] = w2 ? s2[k + 1] : s2[k];
      s2[15] = w2 ? INF64 : s2[15];
    }
  }
  if (vrow) idxg[((size_t)b * 512 + nrow) * 16 + d] = res;
}

// ---------------- Kernel C: edge MLP — R8 shape, L1 dedup + W2 hi-only -------------
// L1: W1p slabs 4-7 duplicate 0-3 (mode-0 pack) -> 2 phases of 2 unique slabs; each
// phase runs 4 s-iters (hi/lo x inner). Same MFMA count/order-class as R8, half the
// staging. L2: W2_lo dropped (error contribution ~4e-4 << threshold) -> 2 phases,
// 64 MFMAs. Barriers 16 -> 8, staging 128 KB -> 64 KB, MFMA 256 -> 192.
__global__ void __launch_bounds__(256) kedge(const bf16_t* __restrict__ xhi,
    const bf16_t* __restrict__ xlo, const int* __restrict__ idxg,
    const int* __restrict__ vlist, const int* __restrict__ vcnt,
    const bf16_t* __restrict__ W1p, const bf16_t* __restrict__ W2p,
    const float* __restrict__ be1, const float* __restrict__ be2,
    float* __restrict__ pooled) {
  const int bb = blockIdx.x >> 6, tile = blockIdx.x & 63;
  const int nv = vcnt[bb];
  if (tile * 8 >= nv) return;  // block-uniform, before any barrier
  __shared__ __align__(16) bf16_t wbuf[8192];          // 16 KB: 2 slabs per phase
  __shared__ __align__(16) bf16_t hfrag[4][2][2048];   // 32 KB
  const int t = threadIdx.x, lane = t & 63, w = t >> 6;
  const int q = lane >> 4, e = lane & 15;

  int gid[2]; bool act[2]; int sv[2];
#pragma unroll
  for (int u = 0; u < 2; ++u) {
    const int slot = tile * 8 + w * 2 + u;
    act[u] = (slot < nv);
    gid[u] = act[u] ? (bb * 512 + vlist[bb * 512 + slot]) : 0;
    sv[u] = act[u] ? idxg[(size_t)gid[u] * 16 + e] : 0;
  }

  f32x4 acc[2][8];
#pragma unroll
  for (int u = 0; u < 2; ++u)
#pragma unroll
    for (int nt = 0; nt < 8; ++nt) acc[u][nt] = zero4();

  // ---- Layer 1: 2 phases (ph=0 receiver slabs {0,1}, ph=1 sender slabs {2,3}) ----
  for (int ph = 0; ph < 2; ++ph) {
    __syncthreads();
    {
      const uint4* src = (const uint4*)(W1p + (size_t)ph * 8192);
      uint4* dst = (uint4*)wbuf;
#pragma unroll
      for (int i = 0; i < 4; ++i) dst[t + 256 * i] = src[t + 256 * i];
    }
    __syncthreads();
#pragma unroll
    for (int k = 0; k < 4; ++k) {
      const int inner = k & 1;
      const bool wantlo = (k >> 1) != 0;
      const bf16_t* plane = wantlo ? xlo : xhi;
      const int col = inner * 32 + q * 8;
      bf16x8 af[2];
#pragma unroll
      for (int u = 0; u < 2; ++u) {
        if (act[u]) {
          const int row = ph ? (bb * 512 + sv[u]) : gid[u];
          af[u] = *(const bf16x8*)(plane + (size_t)row * 64 + col);
        }
      }
#pragma unroll
      for (int nt = 0; nt < 8; ++nt) {
        const bf16x8 bfv = *(const bf16x8*)(wbuf + inner * 4096 + (nt * 64 + lane) * 8);
#pragma unroll
        for (int u = 0; u < 2; ++u)
          if (act[u]) acc[u][nt] = __builtin_amdgcn_mfma_f32_16x16x32_bf16(af[u], bfv, acc[u][nt], 0, 0, 0);
      }
    }
  }

  // ---- Epilogue 1: bias+relu -> bf16 hi -> per-wave lane-linear A-frag buffer ----
#pragma unroll
  for (int u = 0; u < 2; ++u) {
    if (act[u]) {
#pragma unroll
      for (int nt = 0; nt < 8; ++nt) {
        const int cc = nt * 16 + e;
        const float bv = be1[cc];
        const int base = ((cc >> 5) * 64 + (q * 4) + 16 * ((cc >> 3) & 3)) * 8 + (cc & 7);
#pragma unroll
        for (int r = 0; r < 4; ++r) {
          float h = fmaxf(acc[u][nt][r] + bv, 0.f);
          hfrag[w][u][base + r * 8] = f2b(h);
        }
      }
    }
  }

  // ---- Layer 2: 2 phases x 2 slabs, W2 hi only (s = p2*2+sl in 0..3) ----
#pragma unroll
  for (int u = 0; u < 2; ++u)
#pragma unroll
    for (int nt = 0; nt < 8; ++nt) acc[u][nt] = zero4();

  for (int p2 = 0; p2 < 2; ++p2) {
    __syncthreads();
    {
      const uint4* src = (const uint4*)(W2p + (size_t)p2 * 8192);
      uint4* dst = (uint4*)wbuf;
#pragma unroll
      for (int i = 0; i < 4; ++i) dst[t + 256 * i] = src[t + 256 * i];
    }
    __syncthreads();
#pragma unroll
    for (int sl = 0; sl < 2; ++sl) {
      const int f = p2 * 2 + sl;
      bf16x8 af[2];
#pragma unroll
      for (int u = 0; u < 2; ++u)
        if (act[u]) af[u] = *(const bf16x8*)(&hfrag[w][u][(f * 64 + lane) * 8]);
#pragma unroll
      for (int nt = 0; nt < 8; ++nt) {
        const bf16x8 bfv = *(const bf16x8*)(wbuf + sl * 4096 + (nt * 64 + lane) * 8);
#pragma unroll
        for (int u = 0; u < 2; ++u)
          if (act[u]) acc[u][nt] = __builtin_amdgcn_mfma_f32_16x16x32_bf16(af[u], bfv, acc[u][nt], 0, 0, 0);
      }
    }
  }

  // ---- Epilogue 2: bias+relu, mean over 16 edges (cnt==16 exactly) ----
#pragma unroll
  for (int u = 0; u < 2; ++u) {
    if (act[u]) {
#pragma unroll
      for (int nt = 0; nt < 8; ++nt) {
        const float bv = be2[nt * 16 + e];
        float part = 0.f;
#pragma unroll
        for (int r = 0; r < 4; ++r) part += fmaxf(acc[u][nt][r] + bv, 0.f);
        part += __shfl_xor(part, 16, 64);
        part += __shfl_xor(part, 32, 64);
        if (lane < 16) pooled[(size_t)gid[u] * 128 + nt * 16 + lane] = part * 0.0625f;
      }
    }
  }
}

// ---------------- Kernel D: node MLP — r9 L1 + Wn2 hi-only single-phase L2 ---------
__global__ void __launch_bounds__(256) knode(const float* __restrict__ x,
    const float* __restrict__ pooled, const int* __restrict__ mask,
    const bf16_t* __restrict__ Wn1p, const bf16_t* __restrict__ Wn2p,
    const float* __restrict__ bn1, const float* __restrict__ bn2,
    float* __restrict__ out) {
  __shared__ __align__(16) bf16_t wbuf[8192];          // 16 KB
  __shared__ __align__(16) bf16_t hfrag[4][2][2048];   // 32 KB
  const int t = threadIdx.x, lane = t & 63, w = t >> 6;
  const int q = lane >> 4, e = lane & 15;
  int nodebase[2];
#pragma unroll
  for (int u = 0; u < 2; ++u) nodebase[u] = (blockIdx.x * 8 + w * 2 + u) * 16;

  f32x4 acc[2][8];
#pragma unroll
  for (int u = 0; u < 2; ++u)
#pragma unroll
    for (int nt = 0; nt < 8; ++nt) acc[u][nt] = zero4();

  // ---- Layer 1: 3 phases x (2 unique slabs, 4 s-iters) ----
#pragma unroll
  for (int ph = 0; ph < 3; ++ph) {
    __syncthreads();
    {
      const uint4* src = (const uint4*)(Wn1p + (size_t)ph * 8192);
      uint4* dst = (uint4*)wbuf;
#pragma unroll
      for (int i = 0; i < 4; ++i) dst[t + 256 * i] = src[t + 256 * i];
    }
    __syncthreads();
#pragma unroll
    for (int k = 0; k < 4; ++k) {
      const int s = 2 * ph + (k & 1) + (k >> 1) * 6;
      const bool wantlo = (s >= 6);
      const int sr = wantlo ? (s - 6) : s;
      const int col = sr * 32 + q * 8;  // [0,192)
      bf16x8 af[2];
#pragma unroll
      for (int u = 0; u < 2; ++u) {
        const int node = nodebase[u] + e;
        const float* p = (col < 64) ? (x + (size_t)node * 64 + col)
                                    : (pooled + (size_t)node * 128 + (col - 64));
        af[u] = make_frag(p, wantlo);
      }
      const int bslab = s & 1;
#pragma unroll
      for (int nt = 0; nt < 8; ++nt) {
        const bf16x8 bfv = *(const bf16x8*)(wbuf + bslab * 4096 + (nt * 64 + lane) * 8);
#pragma unroll
        for (int u = 0; u < 2; ++u)
          acc[u][nt] = __builtin_amdgcn_mfma_f32_16x16x32_bf16(af[u], bfv, acc[u][nt], 0, 0, 0);
      }
    }
  }

  // ---- Epilogue 1 (wave-private hfrag, no barrier) ----
#pragma unroll
  for (int u = 0; u < 2; ++u) {
#pragma unroll
    for (int nt = 0; nt < 8; ++nt) {
      const int cc = nt * 16 + e;
      const float bv = bn1[cc];
      const int base = ((cc >> 5) * 64 + (q * 4) + 16 * ((cc >> 3) & 3)) * 8 + (cc & 7);
#pragma unroll
      for (int r = 0; r < 4; ++r) {
        float h = fmaxf(acc[u][nt][r] + bv, 0.f);
        hfrag[w][u][base + r * 8] = f2b(h);
      }
    }
  }

  // ---- Layer 2: ONE phase (Wn2 hi slabs 0-3, 16 KB), 4 s-iters ----
  f32x4 acc2[2][4];
#pragma unroll
  for (int u = 0; u < 2; ++u)
#pragma unroll
    for (int nt = 0; nt < 4; ++nt) acc2[u][nt] = zero4();

  __syncthreads();
  {
    const uint4* src = (const uint4*)Wn2p;
    uint4* dst = (uint4*)wbuf;
#pragma unroll
    for (int i = 0; i < 4; ++i) dst[t + 256 * i] = src[t + 256 * i];
  }
  __syncthreads();
#pragma unroll
  for (int sl = 0; sl < 4; ++sl) {
    bf16x8 af[2];
#pragma unroll
    for (int u = 0; u < 2; ++u)
      af[u] = *(const bf16x8*)(&hfrag[w][u][(sl * 64 + lane) * 8]);
#pragma unroll
    for (int nt = 0; nt < 4; ++nt) {
      const bf16x8 bfv = *(const bf16x8*)(wbuf + sl * 2048 + (nt * 64 + lane) * 8);
#pragma unroll
      for (int u = 0; u < 2; ++u)
        acc2[u][nt] = __builtin_amdgcn_mfma_f32_16x16x32_bf16(af[u], bfv, acc2[u][nt], 0, 0, 0);
    }
  }

  // ---- Final: + bn2, * mask, store ----
#pragma unroll
  for (int u = 0; u < 2; ++u) {
    int mm[4];
#pragma unroll
    for (int r = 0; r < 4; ++r) mm[r] = mask[nodebase[u] + q * 4 + r];
#pragma unroll
    for (int nt = 0; nt < 4; ++nt) {
      const float bv = bn2[nt * 16 + e];
#pragma unroll
      for (int r = 0; r < 4; ++r) {
        const int node = nodebase[u] + q * 4 + r;
        out[(size_t)node * 64 + nt * 16 + e] = (acc2[u][nt][r] + bv) * (float)mm[r];
      }
    }
  }
}

// ---------------- Launch ----------------
extern "C" void kernel_launch(void* const* d_in, const int* in_sizes, int n_in,
                              void* d_out, int out_size, void* d_ws, size_t ws_size,
                              hipStream_t stream) {
  const float* nodes = (const float*)d_in[0];
  const int*   mask  = (const int*)d_in[1];
  const float* We1   = (const float*)d_in[2];
  const float* be1   = (const float*)d_in[3];
  const float* We2   = (const float*)d_in[4];
  const float* be2   = (const float*)d_in[5];
  const float* Wn1   = (const float*)d_in[6];
  const float* bn1   = (const float*)d_in[7];
  const float* Wn2   = (const float*)d_in[8];
  const float* bn2   = (const float*)d_in[9];
  float* out = (float*)d_out;

  char* p = (char*)d_ws;
  auto alloc = [&](size_t bytes) -> char* {
    char* r = p;
    p += (bytes + 255) & ~(size_t)255;
    return r;
  };
  float*  x      = (float*)alloc((size_t)32768 * 64 * 4);
  bf16_t* xhi    = (bf16_t*)alloc((size_t)32768 * 64 * 2);
  bf16_t* xlo    = (bf16_t*)alloc((size_t)32768 * 64 * 2);
  float*  sq     = (float*)alloc((size_t)32768 * 4);
  int*    vlist  = (int*)alloc((size_t)32768 * 4);
  int*    vcnt   = (int*)alloc((size_t)64 * 4);
  int*    idxg   = (int*)alloc((size_t)32768 * 16 * 4);
  float*  pooled = (float*)alloc((size_t)32768 * 128 * 4);
  bf16_t* W1p    = (bf16_t*)alloc((size_t)8 * 8 * 64 * 8 * 2);
  bf16_t* W2p    = (bf16_t*)alloc((size_t)8 * 8 * 64 * 8 * 2);
  bf16_t* Wn1p   = (bf16_t*)alloc((size_t)12 * 8 * 64 * 8 * 2);
  bf16_t* Wn2p   = (bf16_t*)alloc((size_t)8 * 4 * 64 * 8 * 2);
  if ((size_t)(p - (char*)d_ws) > ws_size) return;  // workspace too small -> loud failure

  kfuse<<<640, 256, 0, stream>>>(nodes, mask, We1, We2, Wn1, Wn2,
                                 x, xhi, xlo, sq, vlist, vcnt, W1p, W2p, Wn1p, Wn2p);
  kknn<<<2048, 256, 0, stream>>>(x, sq, vlist, vcnt, idxg);
  kedge<<<4096, 256, 0, stream>>>(xhi, xlo, idxg, vlist, vcnt, W1p, W2p, be1, be2, pooled);
  knode<<<256, 256, 0, stream>>>(x, pooled, mask, Wn1p, Wn2p, bn1, bn2, out);
}